// Round 8
// baseline (759.336 us; speedup 1.0000x reference)
//
#include <hip/hip_runtime.h>
#include <hip/hip_fp16.h>

// ---------------------------------------------------------------------------
// sglayer: k=4 iterations of SpMM (COO segment-sum) then Linear(128->128).
// CSR build (bucket-native): prep (zero bcnt + W->fp16) -> phase A bucket
// partition -> phase B per-bucket LDS sort -> split col[int]/w[fp16] arrays.
// SpMM: FEATURE-SLICED (S=2 x 64 feats): each slice runs all 4 iterations on
// a 12.8 MB working set (vs 25.6) to cut L2 capacity misses. fp16 storage,
// fp32 accumulate, 1 wave/row, paired edges. Linear: MFMA 16x16x32 f16,
// K-chunks read from the two slice buffers.
// ---------------------------------------------------------------------------

#define F 128
#define SLICE_H 64       // halves per slice row (64 feats * 2B = 128 B)
#define CH 2048          // edges staged per block in phase A
#define MAXB 256         // max coarse buckets (N <= 131072)
#define RB_LOG 9         // rows per bucket = 512
#define RB (1 << RB_LOG)
#define CAPB 18432       // bucket region capacity (mean 16384, +16 sigma)

typedef _Float16 half8 __attribute__((ext_vector_type(8)));
typedef float f32x4 __attribute__((ext_vector_type(4)));

// ---- prep: zero bcnt (block nwb) + W -> fp16 (blocks 0..nwb-1) -----------
__global__ void prep_kernel(const float* __restrict__ W, __half* __restrict__ Wh,
                            int nw, int* __restrict__ bcnt, int nwb) {
  int blk = blockIdx.x;
  if (blk == nwb) {
    int t = threadIdx.x;
    if (t < MAXB) bcnt[t] = 0;
  } else {
    int i = blk * 256 + threadIdx.x;
    if (i < nw) Wh[i] = __float2half(W[i]);
  }
}

// ---- Phase A: LDS-staged partition into fixed-capacity bucket regions ----
// mid[b*CAPB + k] entry: ((row & 511) << 17) | col , weight fp32 bits
__global__ __launch_bounds__(256) void bucket_scatter(
    const int* __restrict__ erow, const int* __restrict__ ecol,
    const float* __restrict__ ew, int* __restrict__ bcnt,
    int2* __restrict__ mid, int e, int nb) {
  __shared__ int  rowv[CH];                // 8 KB raw rows
  __shared__ int2 cw[CH];                  // 16 KB raw (col, wbits)
  __shared__ int2 stage[CH];               // 16 KB bucket-grouped
  __shared__ unsigned short sbid[CH];      // 4 KB
  __shared__ int cnt[MAXB], lstart[MAXB], gbase[MAXB], cnt2[MAXB];
  __shared__ int ps[256];
  int tid = threadIdx.x;
  int base = blockIdx.x * CH;
  int tot = e - base; if (tot > CH) tot = CH;
  for (int t = tid; t < nb; t += 256) { cnt[t] = 0; cnt2[t] = 0; }
  __syncthreads();
  for (int j = tid; j < tot; j += 256) {
    int i = base + j;
    int r = erow[i];
    rowv[j] = r;
    cw[j] = make_int2(ecol[i], __float_as_int(ew[i]));
    atomicAdd(&cnt[r >> RB_LOG], 1);
  }
  __syncthreads();
  int v = (tid < nb) ? cnt[tid] : 0;
  ps[tid] = v;
  __syncthreads();
  for (int off = 1; off < 256; off <<= 1) {
    int u = (tid >= off) ? ps[tid - off] : 0;
    __syncthreads();
    ps[tid] += u;
    __syncthreads();
  }
  if (tid < nb) lstart[tid] = ps[tid] - v;
  __syncthreads();
  for (int t = tid; t < nb; t += 256)
    if (cnt[t] > 0) gbase[t] = atomicAdd(&bcnt[t], cnt[t]);
  __syncthreads();
  for (int j = tid; j < tot; j += 256) {
    int r = rowv[j];
    int bb = r >> RB_LOG;
    int k = atomicAdd(&cnt2[bb], 1);
    int p = lstart[bb] + k;
    stage[p] = make_int2(((r & (RB - 1)) << 17) | cw[j].x, cw[j].y);
    sbid[p] = (unsigned short)bb;
  }
  __syncthreads();
  for (int j = tid; j < tot; j += 256) {   // coalesced bucket runs
    int bb = sbid[j];
    mid[(size_t)bb * CAPB + gbase[bb] + (j - lstart[bb])] = stage[j];
  }
}

// ---- Phase B: per-bucket base reduce, LDS hist+scan (rptr), count sort ---
// outputs split arrays: ecols[i] = col, ewh[i] = fp16 weight
__global__ __launch_bounds__(256) void csr_sort(
    const int2* __restrict__ mid, const int* __restrict__ bcnt,
    int* __restrict__ rptr, int* __restrict__ ecols, __half* __restrict__ ewh,
    int n, int nb) {
  __shared__ int rcnt[RB];                 // 2 KB
  __shared__ int rofs[RB];                 // 2 KB (exclusive ofs, then cursor)
  __shared__ int psum[256];                // 1 KB
  __shared__ int2 st[CAPB];                // 144 KB
  int b = blockIdx.x, tid = threadIdx.x;
  int r0 = b << RB_LOG;
  int r1 = r0 + RB; if (r1 > n) r1 = n;
  int nr = r1 - r0;
  int cnt = bcnt[b];
  const int2* src = mid + (size_t)b * CAPB;

  psum[tid] = (tid < b && tid < nb) ? bcnt[tid] : 0;
  __syncthreads();
  for (int off = 128; off > 0; off >>= 1) {
    if (tid < off) psum[tid] += psum[tid + off];
    __syncthreads();
  }
  int bas = psum[0];
  __syncthreads();

  for (int r = tid; r < RB; r += 256) rcnt[r] = 0;
  __syncthreads();
  for (int i = tid; i < cnt; i += 256)
    atomicAdd(&rcnt[((unsigned)src[i].x) >> 17], 1);
  __syncthreads();
  int s2 = rcnt[2 * tid] + rcnt[2 * tid + 1];
  psum[tid] = s2;
  __syncthreads();
  for (int off = 1; off < 256; off <<= 1) {
    int u = (tid >= off) ? psum[tid - off] : 0;
    __syncthreads();
    psum[tid] += u;
    __syncthreads();
  }
  int ex = (tid > 0) ? psum[tid - 1] : 0;
  rofs[2 * tid]     = ex;
  rofs[2 * tid + 1] = ex + rcnt[2 * tid];
  __syncthreads();
  for (int r = tid; r < nr; r += 256) rptr[r0 + r] = bas + rofs[r];
  if (b == nb - 1 && tid == 0) rptr[n] = bas + cnt;
  for (int i = tid; i < cnt; i += 256) {
    int2 ed = src[i];
    int rl  = ((unsigned)ed.x) >> 17;
    int col = ed.x & 0x1FFFF;
    int p = atomicAdd(&rofs[rl], 1);
    st[p] = make_int2(col, ed.y);
  }
  __syncthreads();
  for (int i = tid; i < cnt; i += 256) {
    int2 ed = st[i];
    ecols[bas + i] = ed.x;
    ewh[bas + i]   = __float2half(__int_as_float(ed.y));
  }
}

// ---- sliced SpMM: 64 feats (128 B rows), fp16 in/out, fp32 acc -----------
// 1 wave/row; lanes 0-31 even edge of pair, 32-63 odd; lane owns 2 feats.
__global__ __launch_bounds__(256) void spmm_slice(
    const int* __restrict__ rptr, const int* __restrict__ ecols,
    const __half* __restrict__ ewh,
    const __half* __restrict__ xin, __half* __restrict__ xout, int n) {
  int lane = threadIdx.x & 63;
  int hid = lane >> 5;            // pair member
  int fl  = lane & 31;            // dword (2 feats) within 128 B row slice
  int row = (blockIdx.x << 2) + (threadIdx.x >> 6);
  if (row >= n) return;
  int s = rptr[row], e = rptr[row + 1];
  float2 a0 = make_float2(0.f, 0.f), a1 = make_float2(0.f, 0.f);
  const char* xb = (const char*)xin;

#define GFMA(COL, WH, A)                                                      \
  {                                                                           \
    float w = __half2float(WH);                                               \
    union { int i; __half2 h2; } u;                                           \
    u.i = *(const int*)(xb + ((size_t)(unsigned)(COL) << 7) + (fl << 2));     \
    float2 f = __half22float2(u.h2);                                          \
    A.x = fmaf(w, f.x, A.x); A.y = fmaf(w, f.y, A.y);                         \
  }

  int i = s;
  if ((i & 1) && i < e) {          // align to even index for vector loads
    if (hid == 0) GFMA(ecols[i], ewh[i], a0);
    ++i;
  }
  union { uint u; __half2 h2; } wp0, wp1, wp2, wp3;
  for (; i + 7 < e; i += 8) {      // 4 pairs per iteration
    int2 c0 = *(const int2*)&ecols[i];
    int2 c1 = *(const int2*)&ecols[i + 2];
    int2 c2 = *(const int2*)&ecols[i + 4];
    int2 c3 = *(const int2*)&ecols[i + 6];
    wp0.u = *(const uint*)&ewh[i];
    wp1.u = *(const uint*)&ewh[i + 2];
    wp2.u = *(const uint*)&ewh[i + 4];
    wp3.u = *(const uint*)&ewh[i + 6];
    int k0 = hid ? c0.y : c0.x;  __half w0 = hid ? wp0.h2.y : wp0.h2.x;
    int k1 = hid ? c1.y : c1.x;  __half w1 = hid ? wp1.h2.y : wp1.h2.x;
    int k2 = hid ? c2.y : c2.x;  __half w2 = hid ? wp2.h2.y : wp2.h2.x;
    int k3 = hid ? c3.y : c3.x;  __half w3 = hid ? wp3.h2.y : wp3.h2.x;
    GFMA(k0, w0, a0); GFMA(k1, w1, a1);
    GFMA(k2, w2, a0); GFMA(k3, w3, a1);
  }
  for (; i + 1 < e; i += 2) {
    int2 c0 = *(const int2*)&ecols[i];
    wp0.u = *(const uint*)&ewh[i];
    int k0 = hid ? c0.y : c0.x;  __half w0 = hid ? wp0.h2.y : wp0.h2.x;
    GFMA(k0, w0, a0);
  }
  if (i < e && hid == 0) GFMA(ecols[i], ewh[i], a0);
#undef GFMA

  a0.x += a1.x; a0.y += a1.y;
  a0.x += __shfl_xor(a0.x, 32, 64);
  a0.y += __shfl_xor(a0.y, 32, 64);
  if (hid == 0) {
    __half2 o = __float22half2_rn(a0);
    *(__half2*)((char*)xout + ((size_t)row << 7) + (fl << 2)) = o;
  }
}

// ---- sliced f32->f16: slice s covers float2 cols [32s, 32s+32) -----------
__global__ void f32_to_f16_slice(const float2* __restrict__ in,
                                 __half2* __restrict__ dst, int n, int soff) {
  int t = blockIdx.x * blockDim.x + threadIdx.x;
  if (t >= n * 32) return;
  int row = t >> 5, d = t & 31;
  dst[row * 32 + d] = __float22half2_rn(in[(size_t)row * 64 + soff + d]);
}

// ---- Linear via MFMA 16x16x32 f16: out = [S0|S1](fp16) @ Wh^T + b --------
__global__ __launch_bounds__(256) void linear_mfma(
    const __half* __restrict__ s0, const __half* __restrict__ s1,
    const __half* __restrict__ Wh, const float* __restrict__ b,
    float* __restrict__ out, int n) {
  int lane = threadIdx.x & 63;
  int wv   = threadIdx.x >> 6;
  int rbase = blockIdx.x * 64 + wv * 16;
  if (rbase >= n) return;
  int arow = rbase + (lane & 15);
  if (arow >= n) arow = n - 1;               // clamp; padded rows discarded
  int koff = (lane >> 4) * 8;                // 8 consecutive k per lane

  half8 a0 = *(const half8*)(s0 + (size_t)arow * SLICE_H + 0  + koff);
  half8 a1 = *(const half8*)(s0 + (size_t)arow * SLICE_H + 32 + koff);
  half8 a2 = *(const half8*)(s1 + (size_t)arow * SLICE_H + 0  + koff);
  half8 a3 = *(const half8*)(s1 + (size_t)arow * SLICE_H + 32 + koff);

  int drow0 = rbase + (lane >> 4) * 4;       // D: row=(l>>4)*4+m, col=l&15
  int dcol  = lane & 15;
#pragma unroll
  for (int jt = 0; jt < 8; ++jt) {
    const __half* wrow = Wh + (size_t)(jt * 16 + (lane & 15)) * F + koff;
    half8 b0 = *(const half8*)(wrow + 0);
    half8 b1 = *(const half8*)(wrow + 32);
    half8 b2 = *(const half8*)(wrow + 64);
    half8 b3 = *(const half8*)(wrow + 96);
    f32x4 acc = {0.f, 0.f, 0.f, 0.f};
    acc = __builtin_amdgcn_mfma_f32_16x16x32_f16(a0, b0, acc, 0, 0, 0);
    acc = __builtin_amdgcn_mfma_f32_16x16x32_f16(a1, b1, acc, 0, 0, 0);
    acc = __builtin_amdgcn_mfma_f32_16x16x32_f16(a2, b2, acc, 0, 0, 0);
    acc = __builtin_amdgcn_mfma_f32_16x16x32_f16(a3, b3, acc, 0, 0, 0);
    float bias = b[jt * 16 + dcol];
#pragma unroll
    for (int m = 0; m < 4; ++m) {
      int r = drow0 + m;
      if (r < n) out[(size_t)r * F + jt * 16 + dcol] = acc[m] + bias;
    }
  }
}

extern "C" void kernel_launch(void* const* d_in, const int* in_sizes, int n_in,
                              void* d_out, int out_size, void* d_ws, size_t ws_size,
                              hipStream_t stream) {
  const float* x    = (const float*)d_in[0];
  const int*   erow = (const int*)d_in[1];
  const int*   ecol = (const int*)d_in[2];
  const float* ew   = (const float*)d_in[3];
  const float* W    = (const float*)d_in[4];
  const float* b    = (const float*)d_in[5];
  float* out = (float*)d_out;

  const int N = in_sizes[0] / F;
  const int E = in_sizes[1];

  char* ws = (char*)d_ws;
  size_t off = 0;
  int*    ecols = (int*)(ws + off);    off += (size_t)E * 4;
  __half* ewh   = (__half*)(ws + off); off += (size_t)E * 2;
  off = (off + 255) & ~(size_t)255;
  int*   rptr   = (int*)(ws + off);    off += (size_t)(N + 1) * 4;
  int*   bcnt   = (int*)(ws + off);    off += MAXB * 4;
  off = (off + 255) & ~(size_t)255;
  __half* Wh    = (__half*)(ws + off); off += (size_t)F * F * 2;
  off = (off + 255) & ~(size_t)255;
  // big region (51.2 MB): hosts mid (nb*CAPB int2 <= 28.9 MB) during the CSR
  // build, then 4 slice buffers (S0A,S0B,S1A,S1B, 12.8 MB each). mid is fully
  // consumed by csr_sort before the slice conversions write (stream-serial).
  size_t sbytes = (size_t)N * SLICE_H * 2;   // 12.8 MB
  __half* s0A = (__half*)(ws + off);
  __half* s0B = (__half*)(ws + off + sbytes);
  __half* s1A = (__half*)(ws + off + 2 * sbytes);
  __half* s1B = (__half*)(ws + off + 3 * sbytes);
  int2*   mid = (int2*)s0A;

  const int BK = 256;
  int nb = (N + RB - 1) >> RB_LOG;     // 512-row buckets (<= MAXB)
  int nwb = (F * F + BK - 1) / BK;     // W-conversion blocks

  // --- prep (zero bcnt + W->fp16) and bucket-native CSR build
  prep_kernel<<<nwb + 1, BK, 0, stream>>>(W, Wh, F * F, bcnt, nwb);
  bucket_scatter<<<(E + CH - 1) / CH, 256, 0, stream>>>(erow, ecol, ew, bcnt, mid, E, nb);
  csr_sort<<<nb, 256, 0, stream>>>(mid, bcnt, rptr, ecols, ewh, N, nb);

  // --- per-slice fp16 conversion, then 4 iterations per slice
  int cgrid = (N * 32 + BK - 1) / BK;
  f32_to_f16_slice<<<cgrid, BK, 0, stream>>>((const float2*)x, (__half2*)s0A, N, 0);
  f32_to_f16_slice<<<cgrid, BK, 0, stream>>>((const float2*)x, (__half2*)s1A, N, 32);
  int spmm_grid = (N + 3) / 4;
  // slice 0: A->B->A->B->A
  spmm_slice<<<spmm_grid, 256, 0, stream>>>(rptr, ecols, ewh, s0A, s0B, N);
  spmm_slice<<<spmm_grid, 256, 0, stream>>>(rptr, ecols, ewh, s0B, s0A, N);
  spmm_slice<<<spmm_grid, 256, 0, stream>>>(rptr, ecols, ewh, s0A, s0B, N);
  spmm_slice<<<spmm_grid, 256, 0, stream>>>(rptr, ecols, ewh, s0B, s0A, N);
  // slice 1
  spmm_slice<<<spmm_grid, 256, 0, stream>>>(rptr, ecols, ewh, s1A, s1B, N);
  spmm_slice<<<spmm_grid, 256, 0, stream>>>(rptr, ecols, ewh, s1B, s1A, N);
  spmm_slice<<<spmm_grid, 256, 0, stream>>>(rptr, ecols, ewh, s1A, s1B, N);
  spmm_slice<<<spmm_grid, 256, 0, stream>>>(rptr, ecols, ewh, s1B, s1A, N);

  // --- Linear: [s0A | s1A] (fp16) @ Wh^T + b -> out (fp32), via MFMA
  linear_mfma<<<(N + 63) / 64, 256, 0, stream>>>(s0A, s1A, Wh, b, out, N);
}

// Round 9
// 561.532 us; speedup vs baseline: 1.3523x; 1.3523x over previous
//
#include <hip/hip_runtime.h>
#include <hip/hip_fp16.h>

// ---------------------------------------------------------------------------
// sglayer: k=4 iterations of SpMM (COO segment-sum) then Linear(128->128).
// CSR build (bucket-native): prep (zero bcnt + W->fp16) -> phase A bucket
// partition -> phase B per-bucket LDS sort -> split col[int]/w[fp16] arrays.
// SpMM: fp16 storage / fp32 accumulate, 1 wave/row, WIDE gathers: one
// dwordx4/lane instruction fetches 4 edges' 256B rows (lane-quarter per
// edge), halving gather-instruction count vs 8B/lane. Cross-quarter
// shfl_xor reduce at row end. Linear: MFMA 16x16x32 f16.
// ---------------------------------------------------------------------------

#define F 128
#define CH 2048          // edges staged per block in phase A
#define MAXB 256         // max coarse buckets (N <= 131072)
#define RB_LOG 9         // rows per bucket = 512
#define RB (1 << RB_LOG)
#define CAPB 18432       // bucket region capacity (mean 16384, +16 sigma)

typedef _Float16 half8 __attribute__((ext_vector_type(8)));
typedef float f32x4 __attribute__((ext_vector_type(4)));

// ---- prep: zero bcnt (block nwb) + W -> fp16 (blocks 0..nwb-1) -----------
__global__ void prep_kernel(const float* __restrict__ W, __half* __restrict__ Wh,
                            int nw, int* __restrict__ bcnt, int nwb) {
  int blk = blockIdx.x;
  if (blk == nwb) {
    int t = threadIdx.x;
    if (t < MAXB) bcnt[t] = 0;
  } else {
    int i = blk * 256 + threadIdx.x;
    if (i < nw) Wh[i] = __float2half(W[i]);
  }
}

// ---- Phase A: LDS-staged partition into fixed-capacity bucket regions ----
// mid[b*CAPB + k] entry: ((row & 511) << 17) | col , weight fp32 bits
__global__ __launch_bounds__(256) void bucket_scatter(
    const int* __restrict__ erow, const int* __restrict__ ecol,
    const float* __restrict__ ew, int* __restrict__ bcnt,
    int2* __restrict__ mid, int e, int nb) {
  __shared__ int  rowv[CH];                // 8 KB raw rows
  __shared__ int2 cw[CH];                  // 16 KB raw (col, wbits)
  __shared__ int2 stage[CH];               // 16 KB bucket-grouped
  __shared__ unsigned short sbid[CH];      // 4 KB
  __shared__ int cnt[MAXB], lstart[MAXB], gbase[MAXB], cnt2[MAXB];
  __shared__ int ps[256];
  int tid = threadIdx.x;
  int base = blockIdx.x * CH;
  int tot = e - base; if (tot > CH) tot = CH;
  for (int t = tid; t < nb; t += 256) { cnt[t] = 0; cnt2[t] = 0; }
  __syncthreads();
  for (int j = tid; j < tot; j += 256) {
    int i = base + j;
    int r = erow[i];
    rowv[j] = r;
    cw[j] = make_int2(ecol[i], __float_as_int(ew[i]));
    atomicAdd(&cnt[r >> RB_LOG], 1);
  }
  __syncthreads();
  int v = (tid < nb) ? cnt[tid] : 0;
  ps[tid] = v;
  __syncthreads();
  for (int off = 1; off < 256; off <<= 1) {
    int u = (tid >= off) ? ps[tid - off] : 0;
    __syncthreads();
    ps[tid] += u;
    __syncthreads();
  }
  if (tid < nb) lstart[tid] = ps[tid] - v;
  __syncthreads();
  for (int t = tid; t < nb; t += 256)
    if (cnt[t] > 0) gbase[t] = atomicAdd(&bcnt[t], cnt[t]);
  __syncthreads();
  for (int j = tid; j < tot; j += 256) {
    int r = rowv[j];
    int bb = r >> RB_LOG;
    int k = atomicAdd(&cnt2[bb], 1);
    int p = lstart[bb] + k;
    stage[p] = make_int2(((r & (RB - 1)) << 17) | cw[j].x, cw[j].y);
    sbid[p] = (unsigned short)bb;
  }
  __syncthreads();
  for (int j = tid; j < tot; j += 256) {   // coalesced bucket runs
    int bb = sbid[j];
    mid[(size_t)bb * CAPB + gbase[bb] + (j - lstart[bb])] = stage[j];
  }
}

// ---- Phase B: per-bucket base reduce, LDS hist+scan (rptr), count sort ---
// outputs split arrays: ecols[i] = col, ewh[i] = fp16 weight
__global__ __launch_bounds__(256) void csr_sort(
    const int2* __restrict__ mid, const int* __restrict__ bcnt,
    int* __restrict__ rptr, int* __restrict__ ecols, __half* __restrict__ ewh,
    int n, int nb) {
  __shared__ int rcnt[RB];                 // 2 KB
  __shared__ int rofs[RB];                 // 2 KB (exclusive ofs, then cursor)
  __shared__ int psum[256];                // 1 KB
  __shared__ int2 st[CAPB];                // 144 KB
  int b = blockIdx.x, tid = threadIdx.x;
  int r0 = b << RB_LOG;
  int r1 = r0 + RB; if (r1 > n) r1 = n;
  int nr = r1 - r0;
  int cnt = bcnt[b];
  const int2* src = mid + (size_t)b * CAPB;

  psum[tid] = (tid < b && tid < nb) ? bcnt[tid] : 0;
  __syncthreads();
  for (int off = 128; off > 0; off >>= 1) {
    if (tid < off) psum[tid] += psum[tid + off];
    __syncthreads();
  }
  int bas = psum[0];
  __syncthreads();

  for (int r = tid; r < RB; r += 256) rcnt[r] = 0;
  __syncthreads();
  for (int i = tid; i < cnt; i += 256)
    atomicAdd(&rcnt[((unsigned)src[i].x) >> 17], 1);
  __syncthreads();
  int s2 = rcnt[2 * tid] + rcnt[2 * tid + 1];
  psum[tid] = s2;
  __syncthreads();
  for (int off = 1; off < 256; off <<= 1) {
    int u = (tid >= off) ? psum[tid - off] : 0;
    __syncthreads();
    psum[tid] += u;
    __syncthreads();
  }
  int ex = (tid > 0) ? psum[tid - 1] : 0;
  rofs[2 * tid]     = ex;
  rofs[2 * tid + 1] = ex + rcnt[2 * tid];
  __syncthreads();
  for (int r = tid; r < nr; r += 256) rptr[r0 + r] = bas + rofs[r];
  if (b == nb - 1 && tid == 0) rptr[n] = bas + cnt;
  for (int i = tid; i < cnt; i += 256) {
    int2 ed = src[i];
    int rl  = ((unsigned)ed.x) >> 17;
    int col = ed.x & 0x1FFFF;
    int p = atomicAdd(&rofs[rl], 1);
    st[p] = make_int2(col, ed.y);
  }
  __syncthreads();
  for (int i = tid; i < cnt; i += 256) {
    int2 ed = st[i];
    ecols[bas + i] = ed.x;
    ewh[bas + i]   = __float2half(__int_as_float(ed.y));
  }
}

// ---- SpMM: wide gathers (16B/lane, 4 edges per wave instruction) ---------
// lane-quarter q = lane>>4 owns edge i+q; lane holds 8 feats (fl = lane&15).
__global__ __launch_bounds__(256) void spmm_kernel(
    const int* __restrict__ rptr, const int* __restrict__ ecols,
    const __half* __restrict__ ewh,
    const __half* __restrict__ xin, __half* __restrict__ xout, int n) {
  int lane = threadIdx.x & 63;
  int q  = lane >> 4;             // edge within group-of-4
  int fl = lane & 15;             // 16 B feature chunk within 256 B row
  int row = (blockIdx.x << 2) + (threadIdx.x >> 6);
  if (row >= n) return;
  int s = rptr[row], e = rptr[row + 1];
  float a00 = 0.f, a01 = 0.f, a02 = 0.f, a03 = 0.f;
  float a04 = 0.f, a05 = 0.f, a06 = 0.f, a07 = 0.f;
  float b00 = 0.f, b01 = 0.f, b02 = 0.f, b03 = 0.f;
  float b04 = 0.f, b05 = 0.f, b06 = 0.f, b07 = 0.f;
  const char* xb = (const char*)xin;
  union V { int4 i4; __half2 h2[4]; };

#define UNPACK_FMA(U, W, P)                                                   \
  {                                                                           \
    float2 f0 = __half22float2((U).h2[0]);                                    \
    float2 f1 = __half22float2((U).h2[1]);                                    \
    float2 f2 = __half22float2((U).h2[2]);                                    \
    float2 f3 = __half22float2((U).h2[3]);                                    \
    P##0 = fmaf((W), f0.x, P##0); P##1 = fmaf((W), f0.y, P##1);               \
    P##2 = fmaf((W), f1.x, P##2); P##3 = fmaf((W), f1.y, P##3);               \
    P##4 = fmaf((W), f2.x, P##4); P##5 = fmaf((W), f2.y, P##5);               \
    P##6 = fmaf((W), f3.x, P##6); P##7 = fmaf((W), f3.y, P##7);               \
  }

  int i = s;
  for (; i + 7 < e; i += 8) {      // 8 edges = 2 wide gathers
    int   c0 = ecols[i + q];
    int   c1 = ecols[i + 4 + q];
    float w0 = __half2float(ewh[i + q]);
    float w1 = __half2float(ewh[i + 4 + q]);
    V v0, v1;
    v0.i4 = *(const int4*)(xb + ((size_t)(unsigned)c0 << 8) + (fl << 4));
    v1.i4 = *(const int4*)(xb + ((size_t)(unsigned)c1 << 8) + (fl << 4));
    UNPACK_FMA(v0, w0, a0);
    UNPACK_FMA(v1, w1, b0);
  }
  for (; i < e; i += 4) {          // tail groups of <=4 edges
    int idx = i + q;
    bool ok = idx < e;
    int   c = ecols[ok ? idx : e - 1];
    float w = ok ? __half2float(ewh[idx]) : 0.f;
    V v;
    v.i4 = *(const int4*)(xb + ((size_t)(unsigned)c << 8) + (fl << 4));
    UNPACK_FMA(v, w, a0);
  }
#undef UNPACK_FMA

  a00 += b00; a01 += b01; a02 += b02; a03 += b03;
  a04 += b04; a05 += b05; a06 += b06; a07 += b07;
#define RED(X) X += __shfl_xor(X, 16, 64); X += __shfl_xor(X, 32, 64);
  RED(a00) RED(a01) RED(a02) RED(a03) RED(a04) RED(a05) RED(a06) RED(a07)
#undef RED
  if (q == 0) {
    union V o;
    o.h2[0] = __float22half2_rn(make_float2(a00, a01));
    o.h2[1] = __float22half2_rn(make_float2(a02, a03));
    o.h2[2] = __float22half2_rn(make_float2(a04, a05));
    o.h2[3] = __float22half2_rn(make_float2(a06, a07));
    *(int4*)((char*)xout + ((size_t)row << 8) + (fl << 4)) = o.i4;
  }
}

__global__ void f32_to_f16(const float2* __restrict__ in, __half2* __restrict__ out, int n2) {
  int i = blockIdx.x * blockDim.x + threadIdx.x;
  if (i < n2) out[i] = __float22half2_rn(in[i]);
}

// ---- Linear via MFMA 16x16x32 f16: out = X(fp16) @ Wh^T + b --------------
__global__ __launch_bounds__(256) void linear_mfma(
    const __half* __restrict__ xin, const __half* __restrict__ Wh,
    const float* __restrict__ b, float* __restrict__ out, int n) {
  int lane = threadIdx.x & 63;
  int wv   = threadIdx.x >> 6;
  int rbase = blockIdx.x * 64 + wv * 16;
  if (rbase >= n) return;
  int arow = rbase + (lane & 15);
  if (arow >= n) arow = n - 1;               // clamp; padded rows discarded
  int koff = (lane >> 4) * 8;                // 8 consecutive k per lane

  half8 a0 = *(const half8*)(xin + (size_t)arow * F + 0  + koff);
  half8 a1 = *(const half8*)(xin + (size_t)arow * F + 32 + koff);
  half8 a2 = *(const half8*)(xin + (size_t)arow * F + 64 + koff);
  half8 a3 = *(const half8*)(xin + (size_t)arow * F + 96 + koff);

  int drow0 = rbase + (lane >> 4) * 4;       // D: row=(l>>4)*4+m, col=l&15
  int dcol  = lane & 15;
#pragma unroll
  for (int jt = 0; jt < 8; ++jt) {
    const __half* wrow = Wh + (size_t)(jt * 16 + (lane & 15)) * F + koff;
    half8 b0 = *(const half8*)(wrow + 0);
    half8 b1 = *(const half8*)(wrow + 32);
    half8 b2 = *(const half8*)(wrow + 64);
    half8 b3 = *(const half8*)(wrow + 96);
    f32x4 acc = {0.f, 0.f, 0.f, 0.f};
    acc = __builtin_amdgcn_mfma_f32_16x16x32_f16(a0, b0, acc, 0, 0, 0);
    acc = __builtin_amdgcn_mfma_f32_16x16x32_f16(a1, b1, acc, 0, 0, 0);
    acc = __builtin_amdgcn_mfma_f32_16x16x32_f16(a2, b2, acc, 0, 0, 0);
    acc = __builtin_amdgcn_mfma_f32_16x16x32_f16(a3, b3, acc, 0, 0, 0);
    float bias = b[jt * 16 + dcol];
#pragma unroll
    for (int m = 0; m < 4; ++m) {
      int r = drow0 + m;
      if (r < n) out[(size_t)r * F + jt * 16 + dcol] = acc[m] + bias;
    }
  }
}

extern "C" void kernel_launch(void* const* d_in, const int* in_sizes, int n_in,
                              void* d_out, int out_size, void* d_ws, size_t ws_size,
                              hipStream_t stream) {
  const float* x    = (const float*)d_in[0];
  const int*   erow = (const int*)d_in[1];
  const int*   ecol = (const int*)d_in[2];
  const float* ew   = (const float*)d_in[3];
  const float* W    = (const float*)d_in[4];
  const float* b    = (const float*)d_in[5];
  float* out = (float*)d_out;

  const int N = in_sizes[0] / F;
  const int E = in_sizes[1];

  char* ws = (char*)d_ws;
  size_t off = 0;
  int*    ecols = (int*)(ws + off);    off += (size_t)E * 4;
  __half* ewh   = (__half*)(ws + off); off += (size_t)E * 2;
  off = (off + 255) & ~(size_t)255;
  int*   rptr   = (int*)(ws + off);    off += (size_t)(N + 1) * 4;
  int*   bcnt   = (int*)(ws + off);    off += MAXB * 4;
  off = (off + 255) & ~(size_t)255;
  __half* Wh    = (__half*)(ws + off); off += (size_t)F * F * 2;
  off = (off + 255) & ~(size_t)255;
  // big region (51.2 MB): hosts mid (nb*CAPB int2 <= 28.9 MB) during the CSR
  // build, then the fp16 ping-pong buffers A,B (25.6 MB each). mid is fully
  // consumed by csr_sort before f32_to_f16 writes bufB (stream-serial).
  __half* bufA = (__half*)(ws + off);
  __half* bufB = (__half*)(ws + off + (size_t)N * F * 2);
  int2*   mid  = (int2*)bufA;

  const int BK = 256;
  int nb = (N + RB - 1) >> RB_LOG;     // 512-row buckets (<= MAXB)
  int nwb = (F * F + BK - 1) / BK;     // W-conversion blocks

  // --- prep (zero bcnt + W->fp16) and bucket-native CSR build
  prep_kernel<<<nwb + 1, BK, 0, stream>>>(W, Wh, F * F, bcnt, nwb);
  bucket_scatter<<<(E + CH - 1) / CH, 256, 0, stream>>>(erow, ecol, ew, bcnt, mid, E, nb);
  csr_sort<<<nb, 256, 0, stream>>>(mid, bcnt, rptr, ecols, ewh, N, nb);

  // --- convert x to fp16, then 4 SpMM iterations (ping-pong B <-> A)
  int n2 = N * (F / 2);
  f32_to_f16<<<(n2 + BK - 1) / BK, BK, 0, stream>>>((const float2*)x, (__half2*)bufB, n2);
  int spmm_grid = (N + 3) / 4;
  spmm_kernel<<<spmm_grid, 256, 0, stream>>>(rptr, ecols, ewh, bufB, bufA, N);
  spmm_kernel<<<spmm_grid, 256, 0, stream>>>(rptr, ecols, ewh, bufA, bufB, N);
  spmm_kernel<<<spmm_grid, 256, 0, stream>>>(rptr, ecols, ewh, bufB, bufA, N);
  spmm_kernel<<<spmm_grid, 256, 0, stream>>>(rptr, ecols, ewh, bufA, bufB, N);

  // --- Linear: bufB (fp16) @ Wh^T + b -> out (fp32), via MFMA
  linear_mfma<<<(N + 63) / 64, 256, 0, stream>>>(bufB, Wh, b, out, N);
}